// Round 1
// baseline (2090.931 us; speedup 1.0000x reference)
//
#include <hip/hip_runtime.h>
#include <hip/hip_bf16.h>

#define DI __device__ __forceinline__

DI float gelu_f(float x){ return 0.5f*x*(1.0f + erff(x*0.7071067811865476f)); }
DI float bf2f(__hip_bfloat16 b){ return __bfloat162float(b); }
DI __hip_bfloat16 f2bf(float f){ return __float2bfloat16(f); }
DI float bflo(unsigned u){ return __uint_as_float(u<<16); }
DI float bfhi(unsigned u){ return __uint_as_float(u & 0xffff0000u); }

// ---------------- conv1: inp (3,64,64) -> feat (64,4096) channel-major ----------------
__global__ __launch_bounds__(256) void k_conv1(const float* __restrict__ inp, const float* __restrict__ w,
                                               const float* __restrict__ b, float* __restrict__ feat){
  int idx = blockIdx.x*256 + threadIdx.x;
  int o = idx >> 12, p = idx & 4095, y = p >> 6, x = p & 63;
  float acc = b[o];
  #pragma unroll
  for(int c=0;c<3;c++){
    #pragma unroll
    for(int ky=0;ky<3;ky++){
      int yy = y+ky-1; if((unsigned)yy >= 64u) continue;
      #pragma unroll
      for(int kx=0;kx<3;kx++){
        int xx = x+kx-1; if((unsigned)xx >= 64u) continue;
        acc += inp[c*4096 + yy*64 + xx] * w[o*27 + c*9 + ky*3 + kx];
      }
    }
  }
  feat[o*4096 + p] = acc;
}

// ---------------- conv2: feat (64,4096) -> freqT (4096 pix, 256 ch) pixel-major ----------------
__global__ __launch_bounds__(256) void k_conv2(const float* __restrict__ feat, const float* __restrict__ w,
                                               const float* __restrict__ b, float* __restrict__ freqT){
  __shared__ float ft[9][64];
  int p = blockIdx.x, y = p>>6, x = p&63, t = threadIdx.x;
  for(int l=t; l<576; l+=256){
    int tap = l>>6, c = l&63, ky = tap/3, kx = tap%3;
    int yy = y+ky-1, xx = x+kx-1;
    ft[tap][c] = ((unsigned)yy<64u && (unsigned)xx<64u) ? feat[c*4096 + yy*64 + xx] : 0.0f;
  }
  __syncthreads();
  float acc = b[t];
  const float* wo = w + t*576;
  for(int c=0;c<64;c++){
    #pragma unroll
    for(int tap=0;tap<9;tap++) acc += ft[tap][c]*wo[c*9+tap];
  }
  freqT[p*256 + t] = acc;
}

// ---------------- per-query sampling geometry + result_bil ----------------
__global__ __launch_bounds__(256) void k_sample(const float* __restrict__ coord, const float* __restrict__ inp,
    float* __restrict__ mf, int* __restrict__ mi, float* __restrict__ bil){
  int q = blockIdx.x*256 + threadIdx.x;
  float cy = coord[2*q], cx = coord[2*q+1];
  const float LO = (float)(-1.0 + 1e-6), HI = (float)(1.0 - 1e-6);
  const float ONEG = (float)(-1.0/64.0 + 1e-6), OPOS = (float)(1.0/64.0 + 1e-6);
  float areas[4];
  #pragma unroll
  for(int s=0;s<4;s++){
    float oy = (s<2)?ONEG:OPOS;          // vx in (-1,1) outer
    float ox = (s&1)?OPOS:ONEG;          // vy in (-1,1) inner
    float csy = fminf(fmaxf(cy+oy, LO), HI);
    float csx = fminf(fmaxf(cx+ox, LO), HI);
    float fy = ((csy+1.0f)*64.0f - 1.0f)*0.5f;
    float fx = ((csx+1.0f)*64.0f - 1.0f)*0.5f;
    int iy = (int)rintf(fy); iy = iy<0?0:(iy>63?63:iy);
    int ix = (int)rintf(fx); ix = ix<0?0:(ix>63?63:ix);
    float qcy = -1.0f + (float)(2*iy+1)*0.015625f;
    float qcx = -1.0f + (float)(2*ix+1)*0.015625f;
    float ry = (cy-qcy)*64.0f, rx = (cx-qcx)*64.0f;
    mf[q*16 + 4 + 2*s] = ry; mf[q*16 + 5 + 2*s] = rx;
    areas[s] = fabsf(ry*rx) + 1e-9f;
    mi[q*8 + s] = iy*64 + ix;
  }
  float tot = areas[0]+areas[1]+areas[2]+areas[3];
  #pragma unroll
  for(int s=0;s<4;s++) mf[q*16 + s] = areas[3-s] / tot;   // swapped-area weights

  float fy = ((cy+1.0f)*64.0f - 1.0f)*0.5f;
  float fx = ((cx+1.0f)*64.0f - 1.0f)*0.5f;
  { // bilinear corners for freq sample (no border clamp, zero-mask OOB)
    float y0 = floorf(fy), x0 = floorf(fx);
    float wy = fy-y0, wx = fx-x0;
    int y0i = (int)y0, x0i = (int)x0;
    float cw[4] = {(1.0f-wy)*(1.0f-wx), (1.0f-wy)*wx, wy*(1.0f-wx), wy*wx};
    #pragma unroll
    for(int c2=0;c2<4;c2++){
      int yi = y0i + (c2>>1), xi = x0i + (c2&1);
      bool ok = (yi>=0 && yi<64 && xi>=0 && xi<64);
      int yc = yi<0?0:(yi>63?63:yi), xc = xi<0?0:(xi>63?63:xi);
      mf[q*16 + 12 + c2] = ok ? cw[c2] : 0.0f;
      mi[q*8 + 4 + c2] = yc*64 + xc;
    }
  }
  { // result_bil from inp, border=True
    float fyb = fminf(fmaxf(fy, 0.0f), 63.0f);
    float fxb = fminf(fmaxf(fx, 0.0f), 63.0f);
    float y0 = floorf(fyb), x0 = floorf(fxb);
    float wy = fyb-y0, wx = fxb-x0;
    int y0i = (int)y0, x0i = (int)x0;
    float cw[4] = {(1.0f-wy)*(1.0f-wx), (1.0f-wy)*wx, wy*(1.0f-wx), wy*wx};
    float a0=0,a1=0,a2=0;
    #pragma unroll
    for(int c2=0;c2<4;c2++){
      int yi = y0i + (c2>>1), xi = x0i + (c2&1);
      if(yi>=0 && yi<64 && xi>=0 && xi<64){
        int idx = yi*64+xi; float wgt = cw[c2];
        a0 += inp[idx]*wgt; a1 += inp[4096+idx]*wgt; a2 += inp[8192+idx]*wgt;
      }
    }
    bil[q*3+0]=a0; bil[q*3+1]=a1; bil[q*3+2]=a2;
  }
}

// ---------------- stage-1 MLP via P-gather: h = gelu(gathered + small-rows + bias) ----------------
template<int BR>
__global__ __launch_bounds__(256) void k_stage1(const __hip_bfloat16* __restrict__ P, const float* __restrict__ mf,
    const int* __restrict__ mi, const float* __restrict__ coord, const float* __restrict__ cell,
    const float* __restrict__ W1, const float* __restrict__ b1, __hip_bfloat16* __restrict__ out){
  __shared__ float wsm[11][256];
  int j = threadIdx.x;
  if(BR==0){
    #pragma unroll
    for(int r=0;r<8;r++) wsm[r][j] = W1[r*256 + j];
    wsm[8][j] = W1[1032*256 + j];
    wsm[9][j] = W1[1033*256 + j];
    wsm[10][j] = b1[j];
  } else {
    wsm[0][j] = W1[0*256 + j];
    wsm[1][j] = W1[1*256 + j];
    wsm[2][j] = W1[258*256 + j];
    wsm[3][j] = W1[259*256 + j];
    wsm[4][j] = b1[j];
  }
  __syncthreads();
  int q0 = blockIdx.x*32;
  for(int qq=0;qq<32;qq++){
    int q = q0+qq;
    float acc;
    const float* m = mf + q*16;
    const int* ii = mi + q*8;
    if(BR==0){
      acc = wsm[10][j];
      #pragma unroll
      for(int r=0;r<8;r++) acc += m[4+r]*wsm[r][j];
      float cly = cell[2*q]*64.0f, clx = cell[2*q+1]*64.0f;
      acc += cly*wsm[8][j] + clx*wsm[9][j];
      #pragma unroll
      for(int s=0;s<4;s++) acc += m[s]*bf2f(P[(size_t)ii[s]*1280 + s*256 + j]);
    } else {
      acc = wsm[4][j];
      float cy = coord[2*q], cx = coord[2*q+1];
      float cly = cell[2*q]*64.0f, clx = cell[2*q+1]*64.0f;
      acc += cy*wsm[0][j] + cx*wsm[1][j] + cly*wsm[2][j] + clx*wsm[3][j];
      #pragma unroll
      for(int c2=0;c2<4;c2++) acc += m[12+c2]*bf2f(P[(size_t)ii[4+c2]*1280 + 1024 + j]);
    }
    out[(size_t)q*256 + j] = f2bf(gelu_f(acc));
  }
}

// ---------------- generic tiled GEMM: C = epi(A@B + bias) [+R1][+R2] ----------------
template<int ACT, int NRES, bool ABF, bool OBF>
__global__ __launch_bounds__(256) void k_gemm(const void* __restrict__ Ap, const float* __restrict__ B,
    const float* __restrict__ bias, const __hip_bfloat16* __restrict__ R1, const __hip_bfloat16* __restrict__ R2,
    void* __restrict__ Cp, int M, int N, int K, int lda, int ldb, int ldc){
  __shared__ float As[16][68];   // [k][m] padded
  __shared__ float Bs[16][64];   // [k][n]
  int t = threadIdx.x;
  int m0 = blockIdx.y*64, n0 = blockIdx.x*64;
  int rm = (t>>4)*4, cn = (t&15)*4;
  float acc[4][4] = {{0.0f}};
  int lm = t>>2, lk = (t&3)*4;
  int bk = t>>4, bn = (t&15)*4;
  for(int k0=0;k0<K;k0+=16){
    if(ABF){
      const __hip_bfloat16* ap = (const __hip_bfloat16*)Ap + (size_t)(m0+lm)*lda + k0 + lk;
      uint2 u = *reinterpret_cast<const uint2*>(ap);
      As[lk+0][lm] = bflo(u.x); As[lk+1][lm] = bfhi(u.x);
      As[lk+2][lm] = bflo(u.y); As[lk+3][lm] = bfhi(u.y);
    } else {
      const float* ap = (const float*)Ap + (size_t)(m0+lm)*lda + k0 + lk;
      float4 f = *reinterpret_cast<const float4*>(ap);
      As[lk+0][lm]=f.x; As[lk+1][lm]=f.y; As[lk+2][lm]=f.z; As[lk+3][lm]=f.w;
    }
    {
      const float* bp = B + (size_t)(k0+bk)*ldb + n0 + bn;
      float4 f = *reinterpret_cast<const float4*>(bp);
      Bs[bk][bn+0]=f.x; Bs[bk][bn+1]=f.y; Bs[bk][bn+2]=f.z; Bs[bk][bn+3]=f.w;
    }
    __syncthreads();
    #pragma unroll
    for(int kk=0;kk<16;kk++){
      float4 av = *reinterpret_cast<const float4*>(&As[kk][rm]);
      float4 bv = *reinterpret_cast<const float4*>(&Bs[kk][cn]);
      float a[4] = {av.x,av.y,av.z,av.w};
      float bb[4] = {bv.x,bv.y,bv.z,bv.w};
      #pragma unroll
      for(int i=0;i<4;i++)
        #pragma unroll
        for(int jj=0;jj<4;jj++) acc[i][jj] += a[i]*bb[jj];
    }
    __syncthreads();
  }
  #pragma unroll
  for(int i=0;i<4;i++){
    size_t mrow = (size_t)(m0+rm+i);
    #pragma unroll
    for(int jj=0;jj<4;jj++){
      int n = n0+cn+jj;
      float v = acc[i][jj] + (bias ? bias[n] : 0.0f);
      if(ACT==1) v = gelu_f(v);
      if(NRES>=1) v += bf2f(R1[mrow*ldc + n]);
      if(NRES>=2) v += bf2f(R2[mrow*ldc + n]);
      if(OBF) ((__hip_bfloat16*)Cp)[mrow*ldc + n] = f2bf(v);
      else    ((float*)Cp)[mrow*ldc + n] = v;
    }
  }
}

// ---------------- LN(k),LN(v) + partial kv outer-product reduction (deterministic) ----------------
__global__ __launch_bounds__(256) void k_lnkv(const __hip_bfloat16* __restrict__ qkv,
    const float* __restrict__ kw, const float* __restrict__ kb,
    const float* __restrict__ vw, const float* __restrict__ vb,
    float* __restrict__ kvpart){
  __shared__ float kn[16][16][17];   // [row][h][c] padded
  __shared__ float vn[16][16][17];
  int t = threadIdx.x;
  int r = t>>4, h = t&15;
  int cc = t>>4, dd = t&15;
  float acc[16];
  #pragma unroll
  for(int i=0;i<16;i++) acc[i]=0.0f;
  size_t base = (size_t)blockIdx.x*256;
  for(int ch=0; ch<16; ch++){
    size_t n = base + (size_t)ch*16 + r;
    const __hip_bfloat16* row = qkv + n*768 + 48*h;
    float xk[16], xv[16];
    float mk=0.0f, mv=0.0f;
    #pragma unroll
    for(int c=0;c<16;c++){ xk[c]=bf2f(row[16+c]); xv[c]=bf2f(row[32+c]); mk+=xk[c]; mv+=xv[c]; }
    mk *= 0.0625f; mv *= 0.0625f;
    float sk=0.0f, sv=0.0f;
    #pragma unroll
    for(int c=0;c<16;c++){ float d1=xk[c]-mk; sk+=d1*d1; float d2=xv[c]-mv; sv+=d2*d2; }
    float ik = 1.0f/(sqrtf(sk*(1.0f/15.0f)) + 1e-5f);
    float iv = 1.0f/(sqrtf(sv*(1.0f/15.0f)) + 1e-5f);
    #pragma unroll
    for(int c=0;c<16;c++){
      kn[r][h][c] = kw[h*16+c]*((xk[c]-mk)*ik) + kb[h*16+c];
      vn[r][h][c] = vw[h*16+c]*((xv[c]-mv)*iv) + vb[h*16+c];
    }
    __syncthreads();
    #pragma unroll
    for(int hh=0;hh<16;hh++){
      float s = acc[hh];
      #pragma unroll
      for(int rr=0;rr<16;rr++) s += kn[rr][hh][cc]*vn[rr][hh][dd];
      acc[hh] = s;
    }
    __syncthreads();
  }
  #pragma unroll
  for(int hh=0;hh<16;hh++) kvpart[(size_t)blockIdx.x*4096 + hh*256 + cc*16 + dd] = acc[hh];
}

__global__ __launch_bounds__(256) void k_kvred(const float* __restrict__ kvpart, float* __restrict__ kv){
  int i = blockIdx.x*256 + threadIdx.x;
  float s = 0.0f;
  for(int b2=0;b2<256;b2++) s += kvpart[(size_t)b2*4096 + i];
  kv[i] = s * (1.0f/65536.0f);
}

// ---------------- ret = q @ kv + xin ----------------
__global__ __launch_bounds__(256) void k_ret(const __hip_bfloat16* __restrict__ qkv, const float* __restrict__ kv,
    const __hip_bfloat16* __restrict__ xin, __hip_bfloat16* __restrict__ ret){
  __shared__ float kvs[16][16][17];  // [h][d][c]
  __shared__ float qs[4][16*17];
  int t = threadIdx.x; int h = t>>4, d = t&15;
  for(int l=t;l<4096;l+=256){ int hh=l>>8, cc=(l>>4)&15, dd=l&15; kvs[hh][dd][cc]=kv[l]; }
  __syncthreads();
  size_t n0 = (size_t)blockIdx.x*64;
  for(int nn=0;nn<64;nn+=4){
    #pragma unroll
    for(int i=0;i<4;i++){ size_t n=n0+nn+i; qs[i][h*17+d] = bf2f(qkv[n*768 + 48*h + d]); }
    __syncthreads();
    #pragma unroll
    for(int i=0;i<4;i++){
      size_t n=n0+nn+i;
      float s=0.0f;
      #pragma unroll
      for(int c=0;c<16;c++) s += qs[i][h*17+c]*kvs[h][d][c];
      ret[n*256+t] = f2bf(s + bf2f(xin[n*256+t]));
    }
    __syncthreads();
  }
}

// ---------------- final N=3 GEMM + bias + result_bil -> d_out (fp32) ----------------
__global__ __launch_bounds__(256) void k_final(const __hip_bfloat16* __restrict__ g2, const float* __restrict__ w,
    const float* __restrict__ b, const float* __restrict__ bil, float* __restrict__ out){
  __shared__ float w0[256], w1[256], w2[256];
  int t = threadIdx.x;
  w0[t]=w[t*3]; w1[t]=w[t*3+1]; w2[t]=w[t*3+2];
  __syncthreads();
  size_t q = (size_t)blockIdx.x*256 + t;
  const uint4* row = reinterpret_cast<const uint4*>(g2 + q*256);
  float a0=b[0], a1=b[1], a2=b[2];
  for(int j8=0;j8<32;j8++){
    uint4 u = row[j8];
    unsigned ww[4] = {u.x,u.y,u.z,u.w};
    #pragma unroll
    for(int k2=0;k2<4;k2++){
      int j = j8*8 + k2*2;
      float x0 = bflo(ww[k2]);
      float x1 = bfhi(ww[k2]);
      a0 += x0*w0[j] + x1*w0[j+1];
      a1 += x0*w1[j] + x1*w1[j+1];
      a2 += x0*w2[j] + x1*w2[j+1];
    }
  }
  out[q*3+0]=a0+bil[q*3+0]; out[q*3+1]=a1+bil[q*3+1]; out[q*3+2]=a2+bil[q*3+2];
}

extern "C" void kernel_launch(void* const* d_in, const int* in_sizes, int n_in,
                              void* d_out, int out_size, void* d_ws, size_t ws_size,
                              hipStream_t stream){
  (void)in_sizes; (void)n_in; (void)out_size;
  const float* inp     = (const float*)d_in[0];
  const float* coord   = (const float*)d_in[1];
  const float* cell    = (const float*)d_in[2];
  const float* enc_w   = (const float*)d_in[3];
  const float* enc_b   = (const float*)d_in[4];
  const float* freq_w  = (const float*)d_in[5];
  const float* freq_b  = (const float*)d_in[6];
  const float* out0_w1 = (const float*)d_in[7];
  const float* out0_b1 = (const float*)d_in[8];
  const float* out0_w2 = (const float*)d_in[9];
  const float* out0_b2 = (const float*)d_in[10];
  const float* out1_w1 = (const float*)d_in[11];
  const float* out1_b1 = (const float*)d_in[12];
  const float* out1_w2 = (const float*)d_in[13];
  const float* out1_b2 = (const float*)d_in[14];
  const float* fc1_w1  = (const float*)d_in[15];
  const float* fc1_b1  = (const float*)d_in[16];
  const float* fc1_w2  = (const float*)d_in[17];
  const float* fc1_b2  = (const float*)d_in[18];
  const float* fc2_w1  = (const float*)d_in[19];
  const float* fc2_b1  = (const float*)d_in[20];
  const float* fc2_w2  = (const float*)d_in[21];
  const float* fc2_b2  = (const float*)d_in[22];
  const float* qkv_w[2] = {(const float*)d_in[23], (const float*)d_in[31]};
  const float* qkv_b[2] = {(const float*)d_in[24], (const float*)d_in[32]};
  const float* kln_w[2] = {(const float*)d_in[25], (const float*)d_in[33]};
  const float* kln_b[2] = {(const float*)d_in[26], (const float*)d_in[34]};
  const float* vln_w[2] = {(const float*)d_in[27], (const float*)d_in[35]};
  const float* vln_b[2] = {(const float*)d_in[28], (const float*)d_in[36]};
  const float* proj_w[2] = {(const float*)d_in[29], (const float*)d_in[37]};
  const float* proj_b[2] = {(const float*)d_in[30], (const float*)d_in[38]};

  char* wsp = (char*)d_ws; size_t off = 0;
  auto alloc = [&](size_t bytes)->void*{ void* p = wsp + off; off += (bytes + 255) & ~(size_t)255; return p; };
  float* feat   = (float*)alloc(262144ull*4);
  float* freqT  = (float*)alloc(1048576ull*4);
  __hip_bfloat16* P = (__hip_bfloat16*)alloc(5242880ull*2);
  float* mf     = (float*)alloc(65536ull*16*4);
  int*   mi     = (int*)alloc(65536ull*8*4);
  float* bil    = (float*)alloc(65536ull*3*4);
  float* kvpart = (float*)alloc(256ull*4096*4);
  float* kv0    = (float*)alloc(4096ull*4);
  float* kv1    = (float*)alloc(4096ull*4);
  __hip_bfloat16* bufA = (__hip_bfloat16*)alloc(65536ull*256*2);
  __hip_bfloat16* bufB = (__hip_bfloat16*)alloc(65536ull*256*2);
  __hip_bfloat16* bufC = (__hip_bfloat16*)alloc(65536ull*256*2);
  __hip_bfloat16* QKV  = (__hip_bfloat16*)alloc(65536ull*768*2);
  if(off > ws_size) return;   // insufficient workspace -> leave output zeroed (visible failure)

  k_conv1<<<1024,256,0,stream>>>(inp, enc_w, enc_b, feat);
  k_conv2<<<4096,256,0,stream>>>(feat, freq_w, freq_b, freqT);
  dim3 gP(4,64);
  for(int s=0;s<4;s++)
    k_gemm<0,0,false,true><<<gP,256,0,stream>>>(freqT, out0_w1 + (8+256*s)*256, nullptr, nullptr, nullptr,
                                                P + 256*s, 4096,256,256, 256,256,1280);
  k_gemm<0,0,false,true><<<gP,256,0,stream>>>(freqT, out1_w1 + 2*256, nullptr, nullptr, nullptr,
                                              P + 1024, 4096,256,256, 256,256,1280);
  k_sample<<<256,256,0,stream>>>(coord, inp, mf, mi, bil);

  dim3 g1(4,1024), g3(12,1024);
  for(int br=0;br<2;br++){
    if(br==0) k_stage1<0><<<2048,256,0,stream>>>(P, mf, mi, coord, cell, out0_w1, out0_b1, bufA);
    else      k_stage1<1><<<2048,256,0,stream>>>(P, mf, mi, coord, cell, out1_w1, out1_b1, bufA);
    const float* w2 = br ? out1_w2 : out0_w2;
    const float* b2 = br ? out1_b2 : out0_b2;
    k_gemm<0,0,true,true><<<g1,256,0,stream>>>(bufA, w2, b2, nullptr,nullptr, bufB, 65536,256,256, 256,256,256);
    k_gemm<0,0,true,true><<<g3,256,0,stream>>>(bufB, qkv_w[br], qkv_b[br], nullptr,nullptr, QKV, 65536,768,256, 256,768,768);
    k_lnkv<<<256,256,0,stream>>>(QKV, kln_w[br], kln_b[br], vln_w[br], vln_b[br], kvpart);
    float* kvf = br ? kv1 : kv0;
    k_kvred<<<16,256,0,stream>>>(kvpart, kvf);
    k_ret<<<1024,256,0,stream>>>(QKV, kvf, bufB, bufA);
    if(br==0)
      k_gemm<1,1,true,true><<<g1,256,0,stream>>>(bufA, proj_w[0], proj_b[0], bufB, nullptr, bufC, 65536,256,256, 256,256,256);
    else
      k_gemm<1,2,true,true><<<g1,256,0,stream>>>(bufA, proj_w[1], proj_b[1], bufB, bufC, bufC, 65536,256,256, 256,256,256);
  }
  // bufC = f = x0 + x1
  k_gemm<1,0,true,true><<<g1,256,0,stream>>>(bufC, fc1_w1, fc1_b1, nullptr,nullptr, bufA, 65536,256,256, 256,256,256);
  k_gemm<1,1,true,true><<<g1,256,0,stream>>>(bufA, fc1_w2, fc1_b2, bufC, nullptr, bufB, 65536,256,256, 256,256,256);
  k_gemm<1,0,true,true><<<g1,256,0,stream>>>(bufB, fc2_w1, fc2_b1, nullptr,nullptr, bufA, 65536,256,256, 256,256,256);
  k_final<<<256,256,0,stream>>>(bufA, fc2_w2, fc2_b2, bil, (float*)d_out);
}

// Round 2
// 1038.782 us; speedup vs baseline: 2.0129x; 2.0129x over previous
//
#include <hip/hip_runtime.h>
#include <hip/hip_bf16.h>

#define DI __device__ __forceinline__

DI float gelu_f(float x){ return 0.5f*x*(1.0f + erff(x*0.7071067811865476f)); }
DI float bf2f(__hip_bfloat16 b){ return __bfloat162float(b); }
DI __hip_bfloat16 f2bf(float f){ return __float2bfloat16(f); }
DI float bflo(unsigned u){ return __uint_as_float(u<<16); }
DI float bfhi(unsigned u){ return __uint_as_float(u & 0xffff0000u); }

typedef __attribute__((ext_vector_type(8))) short bf16x8;
typedef __attribute__((ext_vector_type(4))) float f32x4;

template<typename T>
DI void load_lds16(const T* g, T* l){
  __builtin_amdgcn_global_load_lds((const __attribute__((address_space(1))) void*)g,
                                   (__attribute__((address_space(3))) void*)l, 16, 0, 0);
}

// ---------------- conv1: inp (3,64,64) -> feat (64,4096) channel-major ----------------
__global__ __launch_bounds__(256) void k_conv1(const float* __restrict__ inp, const float* __restrict__ w,
                                               const float* __restrict__ b, float* __restrict__ feat){
  int idx = blockIdx.x*256 + threadIdx.x;
  int o = idx >> 12, p = idx & 4095, y = p >> 6, x = p & 63;
  float acc = b[o];
  #pragma unroll
  for(int c=0;c<3;c++){
    #pragma unroll
    for(int ky=0;ky<3;ky++){
      int yy = y+ky-1; if((unsigned)yy >= 64u) continue;
      #pragma unroll
      for(int kx=0;kx<3;kx++){
        int xx = x+kx-1; if((unsigned)xx >= 64u) continue;
        acc += inp[c*4096 + yy*64 + xx] * w[o*27 + c*9 + ky*3 + kx];
      }
    }
  }
  feat[o*4096 + p] = acc;
}

// ---------------- conv2: feat (64,4096) -> freqT (4096 pix, 256 ch) pixel-major ----------------
__global__ __launch_bounds__(256) void k_conv2(const float* __restrict__ feat, const float* __restrict__ w,
                                               const float* __restrict__ b, float* __restrict__ freqT){
  __shared__ float ft[9][64];
  int p = blockIdx.x, y = p>>6, x = p&63, t = threadIdx.x;
  for(int l=t; l<576; l+=256){
    int tap = l>>6, c = l&63, ky = tap/3, kx = tap%3;
    int yy = y+ky-1, xx = x+kx-1;
    ft[tap][c] = ((unsigned)yy<64u && (unsigned)xx<64u) ? feat[c*4096 + yy*64 + xx] : 0.0f;
  }
  __syncthreads();
  float acc = b[t];
  const float* wo = w + t*576;
  for(int c=0;c<64;c++){
    #pragma unroll
    for(int tap=0;tap<9;tap++) acc += ft[tap][c]*wo[c*9+tap];
  }
  freqT[p*256 + t] = acc;
}

// ---------------- per-query sampling geometry + result_bil ----------------
__global__ __launch_bounds__(256) void k_sample(const float* __restrict__ coord, const float* __restrict__ inp,
    float* __restrict__ mf, int* __restrict__ mi, float* __restrict__ bil){
  int q = blockIdx.x*256 + threadIdx.x;
  float cy = coord[2*q], cx = coord[2*q+1];
  const float LO = (float)(-1.0 + 1e-6), HI = (float)(1.0 - 1e-6);
  const float ONEG = (float)(-1.0/64.0 + 1e-6), OPOS = (float)(1.0/64.0 + 1e-6);
  float areas[4];
  #pragma unroll
  for(int s=0;s<4;s++){
    float oy = (s<2)?ONEG:OPOS;
    float ox = (s&1)?OPOS:ONEG;
    float csy = fminf(fmaxf(cy+oy, LO), HI);
    float csx = fminf(fmaxf(cx+ox, LO), HI);
    float fy = ((csy+1.0f)*64.0f - 1.0f)*0.5f;
    float fx = ((csx+1.0f)*64.0f - 1.0f)*0.5f;
    int iy = (int)rintf(fy); iy = iy<0?0:(iy>63?63:iy);
    int ix = (int)rintf(fx); ix = ix<0?0:(ix>63?63:ix);
    float qcy = -1.0f + (float)(2*iy+1)*0.015625f;
    float qcx = -1.0f + (float)(2*ix+1)*0.015625f;
    float ry = (cy-qcy)*64.0f, rx = (cx-qcx)*64.0f;
    mf[q*16 + 4 + 2*s] = ry; mf[q*16 + 5 + 2*s] = rx;
    areas[s] = fabsf(ry*rx) + 1e-9f;
    mi[q*8 + s] = iy*64 + ix;
  }
  float tot = areas[0]+areas[1]+areas[2]+areas[3];
  #pragma unroll
  for(int s=0;s<4;s++) mf[q*16 + s] = areas[3-s] / tot;

  float fy = ((cy+1.0f)*64.0f - 1.0f)*0.5f;
  float fx = ((cx+1.0f)*64.0f - 1.0f)*0.5f;
  {
    float y0 = floorf(fy), x0 = floorf(fx);
    float wy = fy-y0, wx = fx-x0;
    int y0i = (int)y0, x0i = (int)x0;
    float cw[4] = {(1.0f-wy)*(1.0f-wx), (1.0f-wy)*wx, wy*(1.0f-wx), wy*wx};
    #pragma unroll
    for(int c2=0;c2<4;c2++){
      int yi = y0i + (c2>>1), xi = x0i + (c2&1);
      bool ok = (yi>=0 && yi<64 && xi>=0 && xi<64);
      int yc = yi<0?0:(yi>63?63:yi), xc = xi<0?0:(xi>63?63:xi);
      mf[q*16 + 12 + c2] = ok ? cw[c2] : 0.0f;
      mi[q*8 + 4 + c2] = yc*64 + xc;
    }
  }
  {
    float fyb = fminf(fmaxf(fy, 0.0f), 63.0f);
    float fxb = fminf(fmaxf(fx, 0.0f), 63.0f);
    float y0 = floorf(fyb), x0 = floorf(fxb);
    float wy = fyb-y0, wx = fxb-x0;
    int y0i = (int)y0, x0i = (int)x0;
    float cw[4] = {(1.0f-wy)*(1.0f-wx), (1.0f-wy)*wx, wy*(1.0f-wx), wy*wx};
    float a0=0,a1=0,a2=0;
    #pragma unroll
    for(int c2=0;c2<4;c2++){
      int yi = y0i + (c2>>1), xi = x0i + (c2&1);
      if(yi>=0 && yi<64 && xi>=0 && xi<64){
        int idx = yi*64+xi; float wgt = cw[c2];
        a0 += inp[idx]*wgt; a1 += inp[4096+idx]*wgt; a2 += inp[8192+idx]*wgt;
      }
    }
    bil[q*3+0]=a0; bil[q*3+1]=a1; bil[q*3+2]=a2;
  }
}

// ---------------- stage-1 MLP via P-gather ----------------
template<int BR>
__global__ __launch_bounds__(256) void k_stage1(const __hip_bfloat16* __restrict__ P, const float* __restrict__ mf,
    const int* __restrict__ mi, const float* __restrict__ coord, const float* __restrict__ cell,
    const float* __restrict__ W1, const float* __restrict__ b1, __hip_bfloat16* __restrict__ out){
  __shared__ float wsm[11][256];
  int j = threadIdx.x;
  if(BR==0){
    #pragma unroll
    for(int r=0;r<8;r++) wsm[r][j] = W1[r*256 + j];
    wsm[8][j] = W1[1032*256 + j];
    wsm[9][j] = W1[1033*256 + j];
    wsm[10][j] = b1[j];
  } else {
    wsm[0][j] = W1[0*256 + j];
    wsm[1][j] = W1[1*256 + j];
    wsm[2][j] = W1[258*256 + j];
    wsm[3][j] = W1[259*256 + j];
    wsm[4][j] = b1[j];
  }
  __syncthreads();
  int q0 = blockIdx.x*32;
  for(int qq=0;qq<32;qq++){
    int q = q0+qq;
    float acc;
    const float* m = mf + q*16;
    const int* ii = mi + q*8;
    if(BR==0){
      acc = wsm[10][j];
      #pragma unroll
      for(int r=0;r<8;r++) acc += m[4+r]*wsm[r][j];
      float cly = cell[2*q]*64.0f, clx = cell[2*q+1]*64.0f;
      acc += cly*wsm[8][j] + clx*wsm[9][j];
      #pragma unroll
      for(int s=0;s<4;s++) acc += m[s]*bf2f(P[(size_t)ii[s]*1280 + s*256 + j]);
    } else {
      acc = wsm[4][j];
      float cy = coord[2*q], cx = coord[2*q+1];
      float cly = cell[2*q]*64.0f, clx = cell[2*q+1]*64.0f;
      acc += cy*wsm[0][j] + cx*wsm[1][j] + cly*wsm[2][j] + clx*wsm[3][j];
      #pragma unroll
      for(int c2=0;c2<4;c2++) acc += m[12+c2]*bf2f(P[(size_t)ii[4+c2]*1280 + 1024 + j]);
    }
    out[(size_t)q*256 + j] = f2bf(gelu_f(acc));
  }
}

// ---------------- fp32 tiled GEMM (kept for the small P-precompute GEMMs) ----------------
template<int ACT, int NRES, bool ABF, bool OBF>
__global__ __launch_bounds__(256) void k_gemm(const void* __restrict__ Ap, const float* __restrict__ B,
    const float* __restrict__ bias, const __hip_bfloat16* __restrict__ R1, const __hip_bfloat16* __restrict__ R2,
    void* __restrict__ Cp, int M, int N, int K, int lda, int ldb, int ldc){
  __shared__ float As[16][68];
  __shared__ float Bs[16][64];
  int t = threadIdx.x;
  int m0 = blockIdx.y*64, n0 = blockIdx.x*64;
  int rm = (t>>4)*4, cn = (t&15)*4;
  float acc[4][4] = {{0.0f}};
  int lm = t>>2, lk = (t&3)*4;
  int bk = t>>4, bn = (t&15)*4;
  for(int k0=0;k0<K;k0+=16){
    if(ABF){
      const __hip_bfloat16* ap = (const __hip_bfloat16*)Ap + (size_t)(m0+lm)*lda + k0 + lk;
      uint2 u = *reinterpret_cast<const uint2*>(ap);
      As[lk+0][lm] = bflo(u.x); As[lk+1][lm] = bfhi(u.x);
      As[lk+2][lm] = bflo(u.y); As[lk+3][lm] = bfhi(u.y);
    } else {
      const float* ap = (const float*)Ap + (size_t)(m0+lm)*lda + k0 + lk;
      float4 f = *reinterpret_cast<const float4*>(ap);
      As[lk+0][lm]=f.x; As[lk+1][lm]=f.y; As[lk+2][lm]=f.z; As[lk+3][lm]=f.w;
    }
    {
      const float* bp = B + (size_t)(k0+bk)*ldb + n0 + bn;
      float4 f = *reinterpret_cast<const float4*>(bp);
      Bs[bk][bn+0]=f.x; Bs[bk][bn+1]=f.y; Bs[bk][bn+2]=f.z; Bs[bk][bn+3]=f.w;
    }
    __syncthreads();
    #pragma unroll
    for(int kk=0;kk<16;kk++){
      float4 av = *reinterpret_cast<const float4*>(&As[kk][rm]);
      float4 bv = *reinterpret_cast<const float4*>(&Bs[kk][cn]);
      float a[4] = {av.x,av.y,av.z,av.w};
      float bb[4] = {bv.x,bv.y,bv.z,bv.w};
      #pragma unroll
      for(int i=0;i<4;i++)
        #pragma unroll
        for(int jj=0;jj<4;jj++) acc[i][jj] += a[i]*bb[jj];
    }
    __syncthreads();
  }
  #pragma unroll
  for(int i=0;i<4;i++){
    size_t mrow = (size_t)(m0+rm+i);
    #pragma unroll
    for(int jj=0;jj<4;jj++){
      int n = n0+cn+jj;
      float v = acc[i][jj] + (bias ? bias[n] : 0.0f);
      if(ACT==1) v = gelu_f(v);
      if(NRES>=1) v += bf2f(R1[mrow*ldc + n]);
      if(NRES>=2) v += bf2f(R2[mrow*ldc + n]);
      if(OBF) ((__hip_bfloat16*)Cp)[mrow*ldc + n] = f2bf(v);
      else    ((float*)Cp)[mrow*ldc + n] = v;
    }
  }
}

// ---------------- weight convert+transpose: fp32 W[K][N] -> bf16 WT[N][K] ----------------
__global__ __launch_bounds__(256) void k_convT(const float* __restrict__ W, __hip_bfloat16* __restrict__ WT,
                                               int K, int N){
  int idx = blockIdx.x*256 + threadIdx.x;
  if(idx >= K*N) return;
  int k = idx / N, n = idx - k*N;
  WT[(size_t)n*K + k] = f2bf(W[idx]);
}

// ---------------- MFMA bf16 GEMM: C = epi(A@B^T + bias)[+R1][+R2], 128x128 tile, BK=64 ----------------
// A: M x K row-major (lda=K), BT: N x K row-major, C: M x N bf16 (ldc)
// T2 both-sides swizzle: LDS [row][64] bf16, 16B slot s swizzled to s^(row&7);
// global_load_lds writes linearly, so the SOURCE address is pre-swizzled (rule #21).
template<int ACT,int NRES>
__global__ __launch_bounds__(256) void k_gemm_mfma(
    const __hip_bfloat16* __restrict__ A, const __hip_bfloat16* __restrict__ BT,
    const float* __restrict__ bias, const __hip_bfloat16* __restrict__ R1,
    const __hip_bfloat16* __restrict__ R2, __hip_bfloat16* __restrict__ C,
    int M, int N, int K, int ldc){
  __shared__ __align__(1024) __hip_bfloat16 As[128*64];
  __shared__ __align__(1024) __hip_bfloat16 Bs[128*64];
  const int t = threadIdx.x, wave = t>>6, lane = t&63;
  const int m0 = blockIdx.x*128, n0 = blockIdx.y*128;
  const int wr = (wave>>1)*64, wc = (wave&1)*64;
  const int lr = lane&15, lh = lane>>4;
  f32x4 acc[4][4] = {};
  for(int k0=0;k0<K;k0+=64){
    #pragma unroll
    for(int i=0;i<4;i++){
      int c = (wave*4+i)*64 + lane;
      int row = c>>3; int k8 = (c&7) ^ (row&7);      // pre-swizzled source slot
      load_lds16(A  + (size_t)(m0+row)*K + (k0 + k8*8), As + (size_t)(wave*4+i)*512);
      load_lds16(BT + (size_t)(n0+row)*K + (k0 + k8*8), Bs + (size_t)(wave*4+i)*512);
    }
    __syncthreads();
    #pragma unroll
    for(int kk=0;kk<2;kk++){
      bf16x8 af[4], bfr[4];
      #pragma unroll
      for(int m=0;m<4;m++){
        int row = wr + m*16 + lr;
        int p = (kk*4 + lh) ^ (row&7);               // swizzled read
        af[m] = *reinterpret_cast<const bf16x8*>(As + row*64 + p*8);
      }
      #pragma unroll
      for(int n=0;n<4;n++){
        int row = wc + n*16 + lr;
        int p = (kk*4 + lh) ^ (row&7);
        bfr[n] = *reinterpret_cast<const bf16x8*>(Bs + row*64 + p*8);
      }
      #pragma unroll
      for(int m=0;m<4;m++)
        #pragma unroll
        for(int n=0;n<4;n++)
          acc[m][n] = __builtin_amdgcn_mfma_f32_16x16x32_bf16(af[m], bfr[n], acc[m][n], 0,0,0);
    }
    __syncthreads();
  }
  #pragma unroll
  for(int m=0;m<4;m++){
    #pragma unroll
    for(int n=0;n<4;n++){
      int col = n0 + wc + n*16 + lr;
      float bsv = bias ? bias[col] : 0.0f;
      #pragma unroll
      for(int j=0;j<4;j++){
        size_t row = (size_t)(m0 + wr + m*16 + lh*4 + j);
        float v = acc[m][n][j] + bsv;
        if(ACT==1) v = gelu_f(v);
        if(NRES>=1) v += bf2f(R1[row*ldc + col]);
        if(NRES>=2) v += bf2f(R2[row*ldc + col]);
        C[row*ldc + col] = f2bf(v);
      }
    }
  }
}

// ---------------- LN(k),LN(v) + partial kv outer-product reduction ----------------
__global__ __launch_bounds__(256) void k_lnkv(const __hip_bfloat16* __restrict__ qkv,
    const float* __restrict__ kw, const float* __restrict__ kb,
    const float* __restrict__ vw, const float* __restrict__ vb,
    float* __restrict__ kvpart){
  __shared__ float kn[16][16][17];
  __shared__ float vn[16][16][17];
  int t = threadIdx.x;
  int r = t>>4, h = t&15;
  int cc = t>>4, dd = t&15;
  float acc[16];
  #pragma unroll
  for(int i=0;i<16;i++) acc[i]=0.0f;
  size_t base = (size_t)blockIdx.x*256;
  for(int ch=0; ch<16; ch++){
    size_t n = base + (size_t)ch*16 + r;
    const __hip_bfloat16* row = qkv + n*768 + 48*h;
    float xk[16], xv[16];
    float mk=0.0f, mv=0.0f;
    #pragma unroll
    for(int c=0;c<16;c++){ xk[c]=bf2f(row[16+c]); xv[c]=bf2f(row[32+c]); mk+=xk[c]; mv+=xv[c]; }
    mk *= 0.0625f; mv *= 0.0625f;
    float sk=0.0f, sv=0.0f;
    #pragma unroll
    for(int c=0;c<16;c++){ float d1=xk[c]-mk; sk+=d1*d1; float d2=xv[c]-mv; sv+=d2*d2; }
    float ik = 1.0f/(sqrtf(sk*(1.0f/15.0f)) + 1e-5f);
    float iv = 1.0f/(sqrtf(sv*(1.0f/15.0f)) + 1e-5f);
    #pragma unroll
    for(int c=0;c<16;c++){
      kn[r][h][c] = kw[h*16+c]*((xk[c]-mk)*ik) + kb[h*16+c];
      vn[r][h][c] = vw[h*16+c]*((xv[c]-mv)*iv) + vb[h*16+c];
    }
    __syncthreads();
    #pragma unroll
    for(int hh=0;hh<16;hh++){
      float s = acc[hh];
      #pragma unroll
      for(int rr=0;rr<16;rr++) s += kn[rr][hh][cc]*vn[rr][hh][dd];
      acc[hh] = s;
    }
    __syncthreads();
  }
  #pragma unroll
  for(int hh=0;hh<16;hh++) kvpart[(size_t)blockIdx.x*4096 + hh*256 + cc*16 + dd] = acc[hh];
}

__global__ __launch_bounds__(256) void k_kvred(const float* __restrict__ kvpart, float* __restrict__ kv){
  int i = blockIdx.x*256 + threadIdx.x;
  float s = 0.0f;
  for(int b2=0;b2<256;b2++) s += kvpart[(size_t)b2*4096 + i];
  kv[i] = s * (1.0f/65536.0f);
}

// ---------------- ret = q @ kv + xin ----------------
__global__ __launch_bounds__(256) void k_ret(const __hip_bfloat16* __restrict__ qkv, const float* __restrict__ kv,
    const __hip_bfloat16* __restrict__ xin, __hip_bfloat16* __restrict__ ret){
  __shared__ float kvs[16][16][17];
  __shared__ float qs[4][16*17];
  int t = threadIdx.x; int h = t>>4, d = t&15;
  for(int l=t;l<4096;l+=256){ int hh=l>>8, cc=(l>>4)&15, dd=l&15; kvs[hh][dd][cc]=kv[l]; }
  __syncthreads();
  size_t n0 = (size_t)blockIdx.x*64;
  for(int nn=0;nn<64;nn+=4){
    #pragma unroll
    for(int i=0;i<4;i++){ size_t n=n0+nn+i; qs[i][h*17+d] = bf2f(qkv[n*768 + 48*h + d]); }
    __syncthreads();
    #pragma unroll
    for(int i=0;i<4;i++){
      size_t n=n0+nn+i;
      float s=0.0f;
      #pragma unroll
      for(int c=0;c<16;c++) s += qs[i][h*17+c]*kvs[h][d][c];
      ret[n*256+t] = f2bf(s + bf2f(xin[n*256+t]));
    }
    __syncthreads();
  }
}

// ---------------- final N=3 GEMM + bias + result_bil -> d_out (fp32) ----------------
__global__ __launch_bounds__(256) void k_final(const __hip_bfloat16* __restrict__ g2, const float* __restrict__ w,
    const float* __restrict__ b, const float* __restrict__ bil, float* __restrict__ out){
  __shared__ float w0[256], w1[256], w2[256];
  int t = threadIdx.x;
  w0[t]=w[t*3]; w1[t]=w[t*3+1]; w2[t]=w[t*3+2];
  __syncthreads();
  size_t q = (size_t)blockIdx.x*256 + t;
  const uint4* row = reinterpret_cast<const uint4*>(g2 + q*256);
  float a0=b[0], a1=b[1], a2=b[2];
  for(int j8=0;j8<32;j8++){
    uint4 u = row[j8];
    unsigned ww[4] = {u.x,u.y,u.z,u.w};
    #pragma unroll
    for(int k2=0;k2<4;k2++){
      int j = j8*8 + k2*2;
      float x0 = bflo(ww[k2]);
      float x1 = bfhi(ww[k2]);
      a0 += x0*w0[j] + x1*w0[j+1];
      a1 += x0*w1[j] + x1*w1[j+1];
      a2 += x0*w2[j] + x1*w2[j+1];
    }
  }
  out[q*3+0]=a0+bil[q*3+0]; out[q*3+1]=a1+bil[q*3+1]; out[q*3+2]=a2+bil[q*3+2];
}

extern "C" void kernel_launch(void* const* d_in, const int* in_sizes, int n_in,
                              void* d_out, int out_size, void* d_ws, size_t ws_size,
                              hipStream_t stream){
  (void)in_sizes; (void)n_in; (void)out_size;
  const float* inp     = (const float*)d_in[0];
  const float* coord   = (const float*)d_in[1];
  const float* cell    = (const float*)d_in[2];
  const float* enc_w   = (const float*)d_in[3];
  const float* enc_b   = (const float*)d_in[4];
  const float* freq_w  = (const float*)d_in[5];
  const float* freq_b  = (const float*)d_in[6];
  const float* out0_w1 = (const float*)d_in[7];
  const float* out0_b1 = (const float*)d_in[8];
  const float* out0_w2 = (const float*)d_in[9];
  const float* out0_b2 = (const float*)d_in[10];
  const float* out1_w1 = (const float*)d_in[11];
  const float* out1_b1 = (const float*)d_in[12];
  const float* out1_w2 = (const float*)d_in[13];
  const float* out1_b2 = (const float*)d_in[14];
  const float* fc1_w1  = (const float*)d_in[15];
  const float* fc1_b1  = (const float*)d_in[16];
  const float* fc1_w2  = (const float*)d_in[17];
  const float* fc1_b2  = (const float*)d_in[18];
  const float* fc2_w1  = (const float*)d_in[19];
  const float* fc2_b1  = (const float*)d_in[20];
  const float* fc2_w2  = (const float*)d_in[21];
  const float* fc2_b2  = (const float*)d_in[22];
  const float* qkv_w[2] = {(const float*)d_in[23], (const float*)d_in[31]};
  const float* qkv_b[2] = {(const float*)d_in[24], (const float*)d_in[32]};
  const float* kln_w[2] = {(const float*)d_in[25], (const float*)d_in[33]};
  const float* kln_b[2] = {(const float*)d_in[26], (const float*)d_in[34]};
  const float* vln_w[2] = {(const float*)d_in[27], (const float*)d_in[35]};
  const float* vln_b[2] = {(const float*)d_in[28], (const float*)d_in[36]};
  const float* proj_w[2] = {(const float*)d_in[29], (const float*)d_in[37]};
  const float* proj_b[2] = {(const float*)d_in[30], (const float*)d_in[38]};

  char* wsp = (char*)d_ws; size_t off = 0;
  auto alloc = [&](size_t bytes)->void*{ void* p = wsp + off; off += (bytes + 255) & ~(size_t)255; return p; };
  float* feat   = (float*)alloc(262144ull*4);
  float* freqT  = (float*)alloc(1048576ull*4);   // reused for bf16 transposed weights after P build
  __hip_bfloat16* P = (__hip_bfloat16*)alloc(5242880ull*2);
  float* mf     = (float*)alloc(65536ull*16*4);
  int*   mi     = (int*)alloc(65536ull*8*4);
  float* bil    = (float*)alloc(65536ull*3*4);
  float* kvpart = (float*)alloc(256ull*4096*4);
  float* kv0    = (float*)alloc(4096ull*4);
  float* kv1    = (float*)alloc(4096ull*4);
  __hip_bfloat16* bufA = (__hip_bfloat16*)alloc(65536ull*256*2);
  __hip_bfloat16* bufB = (__hip_bfloat16*)alloc(65536ull*256*2);
  __hip_bfloat16* bufC = (__hip_bfloat16*)alloc(65536ull*256*2);
  __hip_bfloat16* QKV  = (__hip_bfloat16*)alloc(65536ull*768*2);
  if(off > ws_size) return;

  // bf16 transposed-weight pointers, overlaid on freqT (dead after P build)
  __hip_bfloat16* wtb = (__hip_bfloat16*)freqT;
  __hip_bfloat16* w2T[2]   = {wtb,          wtb + 65536};
  __hip_bfloat16* qkvT[2]  = {wtb + 131072, wtb + 131072 + 196608};
  __hip_bfloat16* projT[2] = {wtb + 524288, wtb + 589824};
  __hip_bfloat16* fc1w1T   =  wtb + 655360;
  __hip_bfloat16* fc1w2T   =  wtb + 720896;
  __hip_bfloat16* fc2w1T   =  wtb + 786432;

  k_conv1<<<1024,256,0,stream>>>(inp, enc_w, enc_b, feat);
  k_conv2<<<4096,256,0,stream>>>(feat, freq_w, freq_b, freqT);
  dim3 gP(4,64);
  for(int s=0;s<4;s++)
    k_gemm<0,0,false,true><<<gP,256,0,stream>>>(freqT, out0_w1 + (8+256*s)*256, nullptr, nullptr, nullptr,
                                                P + 256*s, 4096,256,256, 256,256,1280);
  k_gemm<0,0,false,true><<<gP,256,0,stream>>>(freqT, out1_w1 + 2*256, nullptr, nullptr, nullptr,
                                              P + 1024, 4096,256,256, 256,256,1280);
  // freqT is now dead -> convert weights into its space
  k_convT<<<256,256,0,stream>>>(out0_w2, w2T[0], 256,256);
  k_convT<<<256,256,0,stream>>>(out1_w2, w2T[1], 256,256);
  k_convT<<<768,256,0,stream>>>(qkv_w[0], qkvT[0], 256,768);
  k_convT<<<768,256,0,stream>>>(qkv_w[1], qkvT[1], 256,768);
  k_convT<<<256,256,0,stream>>>(proj_w[0], projT[0], 256,256);
  k_convT<<<256,256,0,stream>>>(proj_w[1], projT[1], 256,256);
  k_convT<<<256,256,0,stream>>>(fc1_w1, fc1w1T, 256,256);
  k_convT<<<256,256,0,stream>>>(fc1_w2, fc1w2T, 256,256);
  k_convT<<<256,256,0,stream>>>(fc2_w1, fc2w1T, 256,256);

  k_sample<<<256,256,0,stream>>>(coord, inp, mf, mi, bil);

  dim3 gm1(512,2), gm3(512,6);
  for(int br=0;br<2;br++){
    if(br==0) k_stage1<0><<<2048,256,0,stream>>>(P, mf, mi, coord, cell, out0_w1, out0_b1, bufA);
    else      k_stage1<1><<<2048,256,0,stream>>>(P, mf, mi, coord, cell, out1_w1, out1_b1, bufA);
    const float* b2 = br ? out1_b2 : out0_b2;
    k_gemm_mfma<0,0><<<gm1,256,0,stream>>>(bufA, w2T[br], b2, nullptr,nullptr, bufB, 65536,256,256, 256);
    k_gemm_mfma<0,0><<<gm3,256,0,stream>>>(bufB, qkvT[br], qkv_b[br], nullptr,nullptr, QKV, 65536,768,256, 768);
    k_lnkv<<<256,256,0,stream>>>(QKV, kln_w[br], kln_b[br], vln_w[br], vln_b[br], kvpart);
    float* kvf = br ? kv1 : kv0;
    k_kvred<<<16,256,0,stream>>>(kvpart, kvf);
    k_ret<<<1024,256,0,stream>>>(QKV, kvf, bufB, bufA);
    if(br==0)
      k_gemm_mfma<1,1><<<gm1,256,0,stream>>>(bufA, projT[0], proj_b[0], bufB, nullptr, bufC, 65536,256,256, 256);
    else
      k_gemm_mfma<1,2><<<gm1,256,0,stream>>>(bufA, projT[1], proj_b[1], bufB, bufC, bufC, 65536,256,256, 256);
  }
  // bufC = f = x0 + x1
  k_gemm_mfma<1,0><<<gm1,256,0,stream>>>(bufC, fc1w1T, fc1_b1, nullptr,nullptr, bufA, 65536,256,256, 256);
  k_gemm_mfma<1,1><<<gm1,256,0,stream>>>(bufA, fc1w2T, fc1_b2, bufC, nullptr, bufB, 65536,256,256, 256);
  k_gemm_mfma<1,0><<<gm1,256,0,stream>>>(bufB, fc2w1T, fc2_b1, nullptr,nullptr, bufA, 65536,256,256, 256);
  k_final<<<256,256,0,stream>>>(bufA, fc2_w2, fc2_b2, bil, (float*)d_out);
}

// Round 3
// 711.644 us; speedup vs baseline: 2.9382x; 1.4597x over previous
//
#include <hip/hip_runtime.h>
#include <hip/hip_bf16.h>

#define DI __device__ __forceinline__

DI float gelu_f(float x){ return 0.5f*x*(1.0f + erff(x*0.7071067811865476f)); }
DI float bf2f(__hip_bfloat16 b){ return __bfloat162float(b); }
DI __hip_bfloat16 f2bf(float f){ return __float2bfloat16(f); }
DI float bflo(unsigned u){ return __uint_as_float(u<<16); }
DI float bfhi(unsigned u){ return __uint_as_float(u & 0xffff0000u); }

typedef __attribute__((ext_vector_type(8))) short bf16x8;
typedef __attribute__((ext_vector_type(4))) float f32x4;

template<typename T>
DI void load_lds16(const T* g, T* l){
  __builtin_amdgcn_global_load_lds((const __attribute__((address_space(1))) void*)g,
                                   (__attribute__((address_space(3))) void*)l, 16, 0, 0);
}

// ---------------- conv1: inp (3,64,64) -> featP (4096 pix, 64 ch) pixel-major ----------------
__global__ __launch_bounds__(256) void k_conv1(const float* __restrict__ inp, const float* __restrict__ w,
                                               const float* __restrict__ b, float* __restrict__ featP){
  int idx = blockIdx.x*256 + threadIdx.x;
  int o = idx & 63, p = idx >> 6, y = p >> 6, x = p & 63;
  float acc = b[o];
  #pragma unroll
  for(int c=0;c<3;c++){
    #pragma unroll
    for(int ky=0;ky<3;ky++){
      int yy = y+ky-1; if((unsigned)yy >= 64u) continue;
      #pragma unroll
      for(int kx=0;kx<3;kx++){
        int xx = x+kx-1; if((unsigned)xx >= 64u) continue;
        acc += inp[c*4096 + yy*64 + xx] * w[o*27 + c*9 + ky*3 + kx];
      }
    }
  }
  featP[p*64 + o] = acc;
}

// ---------------- im2col: featP -> I[4096][640] bf16, K ordered [tap][c], pad 576..640 = 0 ----------------
__global__ __launch_bounds__(256) void k_im2col(const float* __restrict__ featP, __hip_bfloat16* __restrict__ I){
  int p = blockIdx.x, y = p>>6, x = p&63, t = threadIdx.x;
  #pragma unroll
  for(int it=0; it<3; it++){
    int k = it*256 + t;
    if(k >= 640) break;
    float v = 0.0f;
    if(k < 576){
      int tap = k>>6, c = k&63, ky = tap/3, kx = tap%3;
      int yy = y+ky-1, xx = x+kx-1;
      if((unsigned)yy<64u && (unsigned)xx<64u) v = featP[(yy*64+xx)*64 + c];
    }
    I[(size_t)p*640 + k] = f2bf(v);
  }
}

// ---------------- weight permute: freq_w[256][576] ([o][c*9+tap]) -> wfreqT[256][640] ([o][tap*64+c]) ----------------
__global__ __launch_bounds__(256) void k_wfreq(const float* __restrict__ fw, __hip_bfloat16* __restrict__ wt){
  int o = blockIdx.x, t = threadIdx.x;
  #pragma unroll
  for(int it=0; it<3; it++){
    int k = it*256 + t;
    if(k >= 640) break;
    float v = 0.0f;
    if(k < 576){
      int tap = k>>6, c = k&63;
      v = fw[o*576 + c*9 + tap];
    }
    wt[(size_t)o*640 + k] = f2bf(v);
  }
}

// ---------------- wblkT[1280][256]: gathered rows of out0_w1 / out1_w1 (transposed, bf16) ----------------
__global__ __launch_bounds__(256) void k_wblk(const float* __restrict__ w0, const float* __restrict__ w1,
                                              __hip_bfloat16* __restrict__ wt){
  int j = blockIdx.x, kk = threadIdx.x;
  float v;
  if(j < 1024){
    int s = j>>8, n = j&255;
    v = w0[(8 + 256*s + kk)*256 + n];
  } else {
    v = w1[(2 + kk)*256 + (j-1024)];
  }
  wt[(size_t)j*256 + kk] = f2bf(v);
}

// ---------------- per-query sampling geometry + result_bil ----------------
__global__ __launch_bounds__(256) void k_sample(const float* __restrict__ coord, const float* __restrict__ inp,
    float* __restrict__ mf, int* __restrict__ mi, float* __restrict__ bil){
  int q = blockIdx.x*256 + threadIdx.x;
  float cy = coord[2*q], cx = coord[2*q+1];
  const float LO = (float)(-1.0 + 1e-6), HI = (float)(1.0 - 1e-6);
  const float ONEG = (float)(-1.0/64.0 + 1e-6), OPOS = (float)(1.0/64.0 + 1e-6);
  float areas[4];
  #pragma unroll
  for(int s=0;s<4;s++){
    float oy = (s<2)?ONEG:OPOS;
    float ox = (s&1)?OPOS:ONEG;
    float csy = fminf(fmaxf(cy+oy, LO), HI);
    float csx = fminf(fmaxf(cx+ox, LO), HI);
    float fy = ((csy+1.0f)*64.0f - 1.0f)*0.5f;
    float fx = ((csx+1.0f)*64.0f - 1.0f)*0.5f;
    int iy = (int)rintf(fy); iy = iy<0?0:(iy>63?63:iy);
    int ix = (int)rintf(fx); ix = ix<0?0:(ix>63?63:ix);
    float qcy = -1.0f + (float)(2*iy+1)*0.015625f;
    float qcx = -1.0f + (float)(2*ix+1)*0.015625f;
    float ry = (cy-qcy)*64.0f, rx = (cx-qcx)*64.0f;
    mf[q*16 + 4 + 2*s] = ry; mf[q*16 + 5 + 2*s] = rx;
    areas[s] = fabsf(ry*rx) + 1e-9f;
    mi[q*8 + s] = iy*64 + ix;
  }
  float tot = areas[0]+areas[1]+areas[2]+areas[3];
  #pragma unroll
  for(int s=0;s<4;s++) mf[q*16 + s] = areas[3-s] / tot;

  float fy = ((cy+1.0f)*64.0f - 1.0f)*0.5f;
  float fx = ((cx+1.0f)*64.0f - 1.0f)*0.5f;
  {
    float y0 = floorf(fy), x0 = floorf(fx);
    float wy = fy-y0, wx = fx-x0;
    int y0i = (int)y0, x0i = (int)x0;
    float cw[4] = {(1.0f-wy)*(1.0f-wx), (1.0f-wy)*wx, wy*(1.0f-wx), wy*wx};
    #pragma unroll
    for(int c2=0;c2<4;c2++){
      int yi = y0i + (c2>>1), xi = x0i + (c2&1);
      bool ok = (yi>=0 && yi<64 && xi>=0 && xi<64);
      int yc = yi<0?0:(yi>63?63:yi), xc = xi<0?0:(xi>63?63:xi);
      mf[q*16 + 12 + c2] = ok ? cw[c2] : 0.0f;
      mi[q*8 + 4 + c2] = yc*64 + xc;
    }
  }
  {
    float fyb = fminf(fmaxf(fy, 0.0f), 63.0f);
    float fxb = fminf(fmaxf(fx, 0.0f), 63.0f);
    float y0 = floorf(fyb), x0 = floorf(fxb);
    float wy = fyb-y0, wx = fxb-x0;
    int y0i = (int)y0, x0i = (int)x0;
    float cw[4] = {(1.0f-wy)*(1.0f-wx), (1.0f-wy)*wx, wy*(1.0f-wx), wy*wx};
    float a0=0,a1=0,a2=0;
    #pragma unroll
    for(int c2=0;c2<4;c2++){
      int yi = y0i + (c2>>1), xi = x0i + (c2&1);
      if(yi>=0 && yi<64 && xi>=0 && xi<64){
        int idx = yi*64+xi; float wgt = cw[c2];
        a0 += inp[idx]*wgt; a1 += inp[4096+idx]*wgt; a2 += inp[8192+idx]*wgt;
      }
    }
    bil[q*3+0]=a0; bil[q*3+1]=a1; bil[q*3+2]=a2;
  }
}

// ---------------- stage-1 MLP via P-gather ----------------
template<int BR>
__global__ __launch_bounds__(256) void k_stage1(const __hip_bfloat16* __restrict__ P, const float* __restrict__ mf,
    const int* __restrict__ mi, const float* __restrict__ coord, const float* __restrict__ cell,
    const float* __restrict__ W1, const float* __restrict__ b1, __hip_bfloat16* __restrict__ out){
  __shared__ float wsm[11][256];
  int j = threadIdx.x;
  if(BR==0){
    #pragma unroll
    for(int r=0;r<8;r++) wsm[r][j] = W1[r*256 + j];
    wsm[8][j] = W1[1032*256 + j];
    wsm[9][j] = W1[1033*256 + j];
    wsm[10][j] = b1[j];
  } else {
    wsm[0][j] = W1[0*256 + j];
    wsm[1][j] = W1[1*256 + j];
    wsm[2][j] = W1[258*256 + j];
    wsm[3][j] = W1[259*256 + j];
    wsm[4][j] = b1[j];
  }
  __syncthreads();
  int q0 = blockIdx.x*32;
  for(int qq=0;qq<32;qq++){
    int q = q0+qq;
    float acc;
    const float* m = mf + q*16;
    const int* ii = mi + q*8;
    if(BR==0){
      acc = wsm[10][j];
      #pragma unroll
      for(int r=0;r<8;r++) acc += m[4+r]*wsm[r][j];
      float cly = cell[2*q]*64.0f, clx = cell[2*q+1]*64.0f;
      acc += cly*wsm[8][j] + clx*wsm[9][j];
      #pragma unroll
      for(int s=0;s<4;s++) acc += m[s]*bf2f(P[(size_t)ii[s]*1280 + s*256 + j]);
    } else {
      acc = wsm[4][j];
      float cy = coord[2*q], cx = coord[2*q+1];
      float cly = cell[2*q]*64.0f, clx = cell[2*q+1]*64.0f;
      acc += cy*wsm[0][j] + cx*wsm[1][j] + cly*wsm[2][j] + clx*wsm[3][j];
      #pragma unroll
      for(int c2=0;c2<4;c2++) acc += m[12+c2]*bf2f(P[(size_t)ii[4+c2]*1280 + 1024 + j]);
    }
    out[(size_t)q*256 + j] = f2bf(gelu_f(acc));
  }
}

// ---------------- weight convert+transpose: fp32 W[K][N] -> bf16 WT[N][K] ----------------
__global__ __launch_bounds__(256) void k_convT(const float* __restrict__ W, __hip_bfloat16* __restrict__ WT,
                                               int K, int N){
  int idx = blockIdx.x*256 + threadIdx.x;
  if(idx >= K*N) return;
  int k = idx / N, n = idx - k*N;
  WT[(size_t)n*K + k] = f2bf(W[idx]);
}

// ---------------- MFMA bf16 GEMM: C = epi(A@B^T + bias)[+R1][+R2], 128x128 tile, BK=64 ----------------
template<int ACT,int NRES>
__global__ __launch_bounds__(256) void k_gemm_mfma(
    const __hip_bfloat16* __restrict__ A, const __hip_bfloat16* __restrict__ BT,
    const float* __restrict__ bias, const __hip_bfloat16* __restrict__ R1,
    const __hip_bfloat16* __restrict__ R2, __hip_bfloat16* __restrict__ C,
    int M, int N, int K, int ldc){
  __shared__ __align__(1024) __hip_bfloat16 As[128*64];
  __shared__ __align__(1024) __hip_bfloat16 Bs[128*64];
  const int t = threadIdx.x, wave = t>>6, lane = t&63;
  const int m0 = blockIdx.x*128, n0 = blockIdx.y*128;
  const int wr = (wave>>1)*64, wc = (wave&1)*64;
  const int lr = lane&15, lh = lane>>4;
  f32x4 acc[4][4] = {};
  for(int k0=0;k0<K;k0+=64){
    #pragma unroll
    for(int i=0;i<4;i++){
      int c = (wave*4+i)*64 + lane;
      int row = c>>3; int k8 = (c&7) ^ (row&7);      // pre-swizzled source slot
      load_lds16(A  + (size_t)(m0+row)*K + (k0 + k8*8), As + (size_t)(wave*4+i)*512);
      load_lds16(BT + (size_t)(n0+row)*K + (k0 + k8*8), Bs + (size_t)(wave*4+i)*512);
    }
    __syncthreads();
    #pragma unroll
    for(int kk=0;kk<2;kk++){
      bf16x8 af[4], bfr[4];
      #pragma unroll
      for(int m=0;m<4;m++){
        int row = wr + m*16 + lr;
        int p = (kk*4 + lh) ^ (row&7);               // swizzled read
        af[m] = *reinterpret_cast<const bf16x8*>(As + row*64 + p*8);
      }
      #pragma unroll
      for(int n=0;n<4;n++){
        int row = wc + n*16 + lr;
        int p = (kk*4 + lh) ^ (row&7);
        bfr[n] = *reinterpret_cast<const bf16x8*>(Bs + row*64 + p*8);
      }
      #pragma unroll
      for(int m=0;m<4;m++)
        #pragma unroll
        for(int n=0;n<4;n++)
          acc[m][n] = __builtin_amdgcn_mfma_f32_16x16x32_bf16(af[m], bfr[n], acc[m][n], 0,0,0);
    }
    __syncthreads();
  }
  #pragma unroll
  for(int m=0;m<4;m++){
    #pragma unroll
    for(int n=0;n<4;n++){
      int col = n0 + wc + n*16 + lr;
      float bsv = bias ? bias[col] : 0.0f;
      #pragma unroll
      for(int j=0;j<4;j++){
        size_t row = (size_t)(m0 + wr + m*16 + lh*4 + j);
        float v = acc[m][n][j] + bsv;
        if(ACT==1) v = gelu_f(v);
        if(NRES>=1) v += bf2f(R1[row*ldc + col]);
        if(NRES>=2) v += bf2f(R2[row*ldc + col]);
        C[row*ldc + col] = f2bf(v);
      }
    }
  }
}

// ---------------- LN(k),LN(v) + partial kv outer-product reduction ----------------
__global__ __launch_bounds__(256) void k_lnkv(const __hip_bfloat16* __restrict__ qkv,
    const float* __restrict__ kw, const float* __restrict__ kb,
    const float* __restrict__ vw, const float* __restrict__ vb,
    float* __restrict__ kvpart){
  __shared__ float kn[16][16][17];
  __shared__ float vn[16][16][17];
  int t = threadIdx.x;
  int r = t>>4, h = t&15;
  int cc = t>>4, dd = t&15;
  float acc[16];
  #pragma unroll
  for(int i=0;i<16;i++) acc[i]=0.0f;
  size_t base = (size_t)blockIdx.x*256;
  for(int ch=0; ch<16; ch++){
    size_t n = base + (size_t)ch*16 + r;
    const __hip_bfloat16* row = qkv + n*768 + 48*h;
    float xk[16], xv[16];
    float mk=0.0f, mv=0.0f;
    #pragma unroll
    for(int c=0;c<16;c++){ xk[c]=bf2f(row[16+c]); xv[c]=bf2f(row[32+c]); mk+=xk[c]; mv+=xv[c]; }
    mk *= 0.0625f; mv *= 0.0625f;
    float sk=0.0f, sv=0.0f;
    #pragma unroll
    for(int c=0;c<16;c++){ float d1=xk[c]-mk; sk+=d1*d1; float d2=xv[c]-mv; sv+=d2*d2; }
    float ik = 1.0f/(sqrtf(sk*(1.0f/15.0f)) + 1e-5f);
    float iv = 1.0f/(sqrtf(sv*(1.0f/15.0f)) + 1e-5f);
    #pragma unroll
    for(int c=0;c<16;c++){
      kn[r][h][c] = kw[h*16+c]*((xk[c]-mk)*ik) + kb[h*16+c];
      vn[r][h][c] = vw[h*16+c]*((xv[c]-mv)*iv) + vb[h*16+c];
    }
    __syncthreads();
    #pragma unroll
    for(int hh=0;hh<16;hh++){
      float s = acc[hh];
      #pragma unroll
      for(int rr=0;rr<16;rr++) s += kn[rr][hh][cc]*vn[rr][hh][dd];
      acc[hh] = s;
    }
    __syncthreads();
  }
  #pragma unroll
  for(int hh=0;hh<16;hh++) kvpart[(size_t)blockIdx.x*4096 + hh*256 + cc*16 + dd] = acc[hh];
}

__global__ __launch_bounds__(256) void k_kvred(const float* __restrict__ kvpart, float* __restrict__ kv){
  int i = blockIdx.x*256 + threadIdx.x;
  float s = 0.0f;
  for(int b2=0;b2<256;b2++) s += kvpart[(size_t)b2*4096 + i];
  kv[i] = s * (1.0f/65536.0f);
}

// ---------------- ret = q @ kv + xin ----------------
__global__ __launch_bounds__(256) void k_ret(const __hip_bfloat16* __restrict__ qkv, const float* __restrict__ kv,
    const __hip_bfloat16* __restrict__ xin, __hip_bfloat16* __restrict__ ret){
  __shared__ float kvs[16][16][17];
  __shared__ float qs[4][16*17];
  int t = threadIdx.x; int h = t>>4, d = t&15;
  for(int l=t;l<4096;l+=256){ int hh=l>>8, cc=(l>>4)&15, dd=l&15; kvs[hh][dd][cc]=kv[l]; }
  __syncthreads();
  size_t n0 = (size_t)blockIdx.x*64;
  for(int nn=0;nn<64;nn+=4){
    #pragma unroll
    for(int i=0;i<4;i++){ size_t n=n0+nn+i; qs[i][h*17+d] = bf2f(qkv[n*768 + 48*h + d]); }
    __syncthreads();
    #pragma unroll
    for(int i=0;i<4;i++){
      size_t n=n0+nn+i;
      float s=0.0f;
      #pragma unroll
      for(int c=0;c<16;c++) s += qs[i][h*17+c]*kvs[h][d][c];
      ret[n*256+t] = f2bf(s + bf2f(xin[n*256+t]));
    }
    __syncthreads();
  }
}

// ---------------- final N=3 GEMM + bias + result_bil -> d_out (fp32) ----------------
__global__ __launch_bounds__(256) void k_final(const __hip_bfloat16* __restrict__ g2, const float* __restrict__ w,
    const float* __restrict__ b, const float* __restrict__ bil, float* __restrict__ out){
  __shared__ float w0[256], w1[256], w2[256];
  int t = threadIdx.x;
  w0[t]=w[t*3]; w1[t]=w[t*3+1]; w2[t]=w[t*3+2];
  __syncthreads();
  size_t q = (size_t)blockIdx.x*256 + t;
  const uint4* row = reinterpret_cast<const uint4*>(g2 + q*256);
  float a0=b[0], a1=b[1], a2=b[2];
  for(int j8=0;j8<32;j8++){
    uint4 u = row[j8];
    unsigned ww[4] = {u.x,u.y,u.z,u.w};
    #pragma unroll
    for(int k2=0;k2<4;k2++){
      int j = j8*8 + k2*2;
      float x0 = bflo(ww[k2]);
      float x1 = bfhi(ww[k2]);
      a0 += x0*w0[j] + x1*w0[j+1];
      a1 += x0*w1[j] + x1*w1[j+1];
      a2 += x0*w2[j] + x1*w2[j+1];
    }
  }
  out[q*3+0]=a0+bil[q*3+0]; out[q*3+1]=a1+bil[q*3+1]; out[q*3+2]=a2+bil[q*3+2];
}

extern "C" void kernel_launch(void* const* d_in, const int* in_sizes, int n_in,
                              void* d_out, int out_size, void* d_ws, size_t ws_size,
                              hipStream_t stream){
  (void)in_sizes; (void)n_in; (void)out_size;
  const float* inp     = (const float*)d_in[0];
  const float* coord   = (const float*)d_in[1];
  const float* cell    = (const float*)d_in[2];
  const float* enc_w   = (const float*)d_in[3];
  const float* enc_b   = (const float*)d_in[4];
  const float* freq_w  = (const float*)d_in[5];
  const float* freq_b  = (const float*)d_in[6];
  const float* out0_w1 = (const float*)d_in[7];
  const float* out0_b1 = (const float*)d_in[8];
  const float* out0_w2 = (const float*)d_in[9];
  const float* out0_b2 = (const float*)d_in[10];
  const float* out1_w1 = (const float*)d_in[11];
  const float* out1_b1 = (const float*)d_in[12];
  const float* out1_w2 = (const float*)d_in[13];
  const float* out1_b2 = (const float*)d_in[14];
  const float* fc1_w1  = (const float*)d_in[15];
  const float* fc1_b1  = (const float*)d_in[16];
  const float* fc1_w2  = (const float*)d_in[17];
  const float* fc1_b2  = (const float*)d_in[18];
  const float* fc2_w1  = (const float*)d_in[19];
  const float* fc2_b1  = (const float*)d_in[20];
  const float* fc2_w2  = (const float*)d_in[21];
  const float* fc2_b2  = (const float*)d_in[22];
  const float* qkv_w[2] = {(const float*)d_in[23], (const float*)d_in[31]};
  const float* qkv_b[2] = {(const float*)d_in[24], (const float*)d_in[32]};
  const float* kln_w[2] = {(const float*)d_in[25], (const float*)d_in[33]};
  const float* kln_b[2] = {(const float*)d_in[26], (const float*)d_in[34]};
  const float* vln_w[2] = {(const float*)d_in[27], (const float*)d_in[35]};
  const float* vln_b[2] = {(const float*)d_in[28], (const float*)d_in[36]};
  const float* proj_w[2] = {(const float*)d_in[29], (const float*)d_in[37]};
  const float* proj_b[2] = {(const float*)d_in[30], (const float*)d_in[38]};

  char* wsp = (char*)d_ws; size_t off = 0;
  auto alloc = [&](size_t bytes)->void*{ void* p = wsp + off; off += (bytes + 255) & ~(size_t)255; return p; };
  float* featP  = (float*)alloc(262144ull*4);
  __hip_bfloat16* wtb = (__hip_bfloat16*)alloc(2097152ull*2);  // all bf16 weights
  __hip_bfloat16* P = (__hip_bfloat16*)alloc(5242880ull*2);
  float* mf     = (float*)alloc(65536ull*16*4);
  int*   mi     = (int*)alloc(65536ull*8*4);
  float* bil    = (float*)alloc(65536ull*3*4);
  float* kvpart = (float*)alloc(256ull*4096*4);
  float* kv0    = (float*)alloc(4096ull*4);
  float* kv1    = (float*)alloc(4096ull*4);
  __hip_bfloat16* bufA = (__hip_bfloat16*)alloc(65536ull*256*2);
  __hip_bfloat16* bufB = (__hip_bfloat16*)alloc(65536ull*256*2);
  __hip_bfloat16* bufC = (__hip_bfloat16*)alloc(65536ull*256*2);
  __hip_bfloat16* QKV  = (__hip_bfloat16*)alloc(65536ull*768*2);
  if(off > ws_size) return;

  // weight region layout (bf16 elements)
  __hip_bfloat16* w2T[2]   = {wtb,          wtb + 65536};
  __hip_bfloat16* qkvT[2]  = {wtb + 131072, wtb + 131072 + 196608};
  __hip_bfloat16* projT[2] = {wtb + 524288, wtb + 589824};
  __hip_bfloat16* fc1w1T   =  wtb + 655360;
  __hip_bfloat16* fc1w2T   =  wtb + 720896;
  __hip_bfloat16* fc2w1T   =  wtb + 786432;
  __hip_bfloat16* wfreqT   =  wtb + 851968;   // 256 x 640
  __hip_bfloat16* wblkT    =  wtb + 1015808;  // 1280 x 256
  // transient buffers overlaid on bufA/bufB (dead until k_stage1)
  __hip_bfloat16* I2C   = bufA;               // 4096 x 640
  __hip_bfloat16* freqB = bufB;               // 4096 x 256

  k_conv1<<<1024,256,0,stream>>>(inp, enc_w, enc_b, featP);
  k_im2col<<<4096,256,0,stream>>>(featP, I2C);
  k_wfreq<<<256,256,0,stream>>>(freq_w, wfreqT);
  k_wblk<<<1280,256,0,stream>>>(out0_w1, out1_w1, wblkT);
  k_convT<<<256,256,0,stream>>>(out0_w2, w2T[0], 256,256);
  k_convT<<<256,256,0,stream>>>(out1_w2, w2T[1], 256,256);
  k_convT<<<768,256,0,stream>>>(qkv_w[0], qkvT[0], 256,768);
  k_convT<<<768,256,0,stream>>>(qkv_w[1], qkvT[1], 256,768);
  k_convT<<<256,256,0,stream>>>(proj_w[0], projT[0], 256,256);
  k_convT<<<256,256,0,stream>>>(proj_w[1], projT[1], 256,256);
  k_convT<<<256,256,0,stream>>>(fc1_w1, fc1w1T, 256,256);
  k_convT<<<256,256,0,stream>>>(fc1_w2, fc1w2T, 256,256);
  k_convT<<<256,256,0,stream>>>(fc2_w1, fc2w1T, 256,256);

  // conv2 as MFMA GEMM, then P = freq @ wblk^T in one MFMA GEMM
  dim3 gF(32,2), gPm(32,10);
  k_gemm_mfma<0,0><<<gF,256,0,stream>>>(I2C, wfreqT, freq_b, nullptr,nullptr, freqB, 4096,256,640, 256);
  k_gemm_mfma<0,0><<<gPm,256,0,stream>>>(freqB, wblkT, nullptr, nullptr,nullptr, P, 4096,1280,256, 1280);

  k_sample<<<256,256,0,stream>>>(coord, inp, mf, mi, bil);

  dim3 gm1(512,2), gm3(512,6);
  for(int br=0;br<2;br++){
    if(br==0) k_stage1<0><<<2048,256,0,stream>>>(P, mf, mi, coord, cell, out0_w1, out0_b1, bufA);
    else      k_stage1<1><<<2048,256,0,stream>>>(P, mf, mi, coord, cell, out1_w1, out1_b1, bufA);
    const float* b2 = br ? out1_b2 : out0_b2;
    k_gemm_mfma<0,0><<<gm1,256,0,stream>>>(bufA, w2T[br], b2, nullptr,nullptr, bufB, 65536,256,256, 256);
    k_gemm_mfma<0,0><<<gm3,256,0,stream>>>(bufB, qkvT[br], qkv_b[br], nullptr,nullptr, QKV, 65536,768,256, 768);
    k_lnkv<<<256,256,0,stream>>>(QKV, kln_w[br], kln_b[br], vln_w[br], vln_b[br], kvpart);
    float* kvf = br ? kv1 : kv0;
    k_kvred<<<16,256,0,stream>>>(kvpart, kvf);
    k_ret<<<1024,256,0,stream>>>(QKV, kvf, bufB, bufA);
    if(br==0)
      k_gemm_mfma<1,1><<<gm1,256,0,stream>>>(bufA, projT[0], proj_b[0], bufB, nullptr, bufC, 65536,256,256, 256);
    else
      k_gemm_mfma<1,2><<<gm1,256,0,stream>>>(bufA, projT[1], proj_b[1], bufB, bufC, bufC, 65536,256,256, 256);
  }
  // bufC = f = x0 + x1
  k_gemm_mfma<1,0><<<gm1,256,0,stream>>>(bufC, fc1w1T, fc1_b1, nullptr,nullptr, bufA, 65536,256,256, 256);
  k_gemm_mfma<1,1><<<gm1,256,0,stream>>>(bufA, fc1w2T, fc1_b2, bufC, nullptr, bufB, 65536,256,256, 256);
  k_gemm_mfma<1,0><<<gm1,256,0,stream>>>(bufB, fc2w1T, fc2_b1, nullptr,nullptr, bufA, 65536,256,256, 256);
  k_final<<<256,256,0,stream>>>(bufA, fc2_w2, fc2_b2, bil, (float*)d_out);
}